// Round 1
// baseline (145.402 us; speedup 1.0000x reference)
//
#include <hip/hip_runtime.h>
#include <hip/hip_bf16.h>

#define N_E    500000
#define D_NODE 128
#define D_EDGE 64
#define D_GLOB 64
#define NTILES (N_E / 16)   // 31250 exact

typedef __attribute__((ext_vector_type(8))) short s16x8;
typedef __attribute__((ext_vector_type(4))) float fx4;

__device__ __forceinline__ unsigned short f2bf(float x) {
  union { __hip_bfloat16 h; unsigned short u; } cv;
  cv.h = __float2bfloat16(x);   // RTNE
  return cv.u;
}

// 8 consecutive f32 (32B-aligned) -> bf16x8 fragment
__device__ __forceinline__ s16x8 frag8(const float* p) {
  const fx4* q = (const fx4*)p;
  fx4 a = q[0], b = q[1];
  s16x8 r;
  r[0] = (short)f2bf(a[0]); r[1] = (short)f2bf(a[1]);
  r[2] = (short)f2bf(a[2]); r[3] = (short)f2bf(a[3]);
  r[4] = (short)f2bf(b[0]); r[5] = (short)f2bf(b[1]);
  r[6] = (short)f2bf(b[2]); r[7] = (short)f2bf(b[3]);
  return r;
}

__global__ __launch_bounds__(256, 4) void edge_mlp_kernel(
    const float* __restrict__ src, const float* __restrict__ dst,
    const float* __restrict__ ea,  const float* __restrict__ u,
    const int*   __restrict__ batch,
    const float* __restrict__ W1,  const float* __restrict__ b1,
    const float* __restrict__ W2,  const float* __restrict__ b2,
    float* __restrict__ out)
{
  // W1^T / W2^T as bf16, rows padded so 16 lanes reading a column-slice are
  // only 2-way bank-aliased (free).
  __shared__ unsigned short w1t[32][392];   // [n][k], k<384
  __shared__ unsigned short w2t[64][40];    // [n][k], k<32
  __shared__ float b1s[32];
  __shared__ float b2s[64];
  __shared__ unsigned short hstage[4][16][40]; // per-wave H transpose buffer

  const int tid = threadIdx.x;

  for (int i = tid; i < 384 * 32; i += 256) {   // W1 is [384][32] row-major
    int k = i >> 5, n = i & 31;
    w1t[n][k] = f2bf(W1[i]);
  }
  for (int i = tid; i < 32 * 64; i += 256) {    // W2 is [32][64] row-major
    int k = i >> 6, n = i & 63;
    w2t[n][k] = f2bf(W2[i]);
  }
  if (tid < 32) b1s[tid] = b1[tid];
  if (tid < 64) b2s[tid] = b2[tid];
  __syncthreads();

  const int wave = tid >> 6;
  const int lane = tid & 63;
  const int c  = lane & 15;     // A-row / C-col index
  const int r4 = lane >> 4;     // k-group / C-row group
  const int r8 = r4 * 8;
  unsigned short (*hl)[40] = hstage[wave];

  const int gwave  = blockIdx.x * 4 + wave;
  const int nwaves = gridDim.x * 4;

  const float lam = 1.0507009873554805f;
  const float la  = 1.7580993408473766f;   // lambda*alpha

  for (int tile = gwave; tile < NTILES; tile += nwaves) {
    const int e0   = tile * 16;
    const int arow = e0 + c;

    const float* sp  = src + (size_t)arow * D_NODE + r8;
    const float* dp  = dst + (size_t)arow * D_NODE + r8;
    const float* epp = ea  + (size_t)arow * D_EDGE + r8;
    const int    bt  = batch[arow];
    const float* up  = u   + (size_t)bt * D_GLOB + r8;

    // X tile A-fragments: 12 K-steps of 32 (src 4, dest 4, ea 2, u[batch] 2)
    s16x8 af[12];
    af[0]  = frag8(sp);        af[1]  = frag8(sp + 32);
    af[2]  = frag8(sp + 64);   af[3]  = frag8(sp + 96);
    af[4]  = frag8(dp);        af[5]  = frag8(dp + 32);
    af[6]  = frag8(dp + 64);   af[7]  = frag8(dp + 96);
    af[8]  = frag8(epp);       af[9]  = frag8(epp + 32);
    af[10] = frag8(up);        af[11] = frag8(up + 32);

    fx4 acc0 = {0.f, 0.f, 0.f, 0.f};
    fx4 acc1 = {0.f, 0.f, 0.f, 0.f};
#pragma unroll
    for (int kk = 0; kk < 12; ++kk) {
      s16x8 bf0 = *(const s16x8*)&w1t[c][kk * 32 + r8];
      s16x8 bf1 = *(const s16x8*)&w1t[c + 16][kk * 32 + r8];
      acc0 = __builtin_amdgcn_mfma_f32_16x16x32_bf16(af[kk], bf0, acc0, 0, 0, 0);
      acc1 = __builtin_amdgcn_mfma_f32_16x16x32_bf16(af[kk], bf1, acc1, 0, 0, 0);
    }

    // bias + SELU, stage H as bf16 for the layout transpose (C->A)
#pragma unroll
    for (int t = 0; t < 2; ++t) {
      const float bb = b1s[c + 16 * t];
      fx4 a = t ? acc1 : acc0;
#pragma unroll
      for (int r = 0; r < 4; ++r) {
        float v = a[r] + bb;
        v = v > 0.f ? lam * v : la * (__expf(v) - 1.f);
        hl[r4 * 4 + r][c + 16 * t] = f2bf(v);
      }
    }
    __builtin_amdgcn_sched_barrier(0);  // keep ds_writes before the ds_read below

    // Layer 2: one K-step (K=32), 4 N-tiles; bias folded into C-init.
    s16x8 a2 = *(const s16x8*)&hl[c][r8];
    fx4 o0, o1, o2, o3;
    { float bb = b2s[c];      o0 = (fx4){bb, bb, bb, bb}; }
    { float bb = b2s[c + 16]; o1 = (fx4){bb, bb, bb, bb}; }
    { float bb = b2s[c + 32]; o2 = (fx4){bb, bb, bb, bb}; }
    { float bb = b2s[c + 48]; o3 = (fx4){bb, bb, bb, bb}; }
    o0 = __builtin_amdgcn_mfma_f32_16x16x32_bf16(a2, *(const s16x8*)&w2t[c][r8],      o0, 0, 0, 0);
    o1 = __builtin_amdgcn_mfma_f32_16x16x32_bf16(a2, *(const s16x8*)&w2t[c + 16][r8], o1, 0, 0, 0);
    o2 = __builtin_amdgcn_mfma_f32_16x16x32_bf16(a2, *(const s16x8*)&w2t[c + 32][r8], o2, 0, 0, 0);
    o3 = __builtin_amdgcn_mfma_f32_16x16x32_bf16(a2, *(const s16x8*)&w2t[c + 48][r8], o3, 0, 0, 0);

#pragma unroll
    for (int r = 0; r < 4; ++r) {
      float* op = out + (size_t)(e0 + r4 * 4 + r) * 64 + c;
      op[0]  = o0[r];
      op[16] = o1[r];
      op[32] = o2[r];
      op[48] = o3[r];
    }
  }
}

extern "C" void kernel_launch(void* const* d_in, const int* in_sizes, int n_in,
                              void* d_out, int out_size, void* d_ws, size_t ws_size,
                              hipStream_t stream) {
  const float* src   = (const float*)d_in[0];
  const float* dst   = (const float*)d_in[1];
  const float* ea    = (const float*)d_in[2];
  const float* u     = (const float*)d_in[3];
  const int*   batch = (const int*)d_in[4];
  const float* W1    = (const float*)d_in[5];
  const float* b1    = (const float*)d_in[6];
  const float* W2    = (const float*)d_in[7];
  const float* b2    = (const float*)d_in[8];
  float* out = (float*)d_out;

  hipLaunchKernelGGL(edge_mlp_kernel, dim3(2048), dim3(256), 0, stream,
                     src, dst, ea, u, batch, W1, b1, W2, b2, out);
}